// Round 4
// baseline (219.307 us; speedup 1.0000x reference)
//
#include <hip/hip_runtime.h>
#include <hip/hip_bf16.h>
#include <stdint.h>

// Problem constants
#define BB 8
#define SS 2048
#define NEXP 16
#define DIN 1024
#define DOUT 1024

typedef short bf16x8 __attribute__((ext_vector_type(8)));
typedef float floatx4 __attribute__((ext_vector_type(4)));

// s_waitcnt immediates: [3:0] vmcnt lo, [6:4] expcnt, [11:8] lgkmcnt, [15:14] vmcnt hi
#define WAIT_VM0()   __builtin_amdgcn_s_waitcnt(0x0f70)  // vmcnt(0), lgkm/exp free
#define WAIT_LGKM0() __builtin_amdgcn_s_waitcnt(0xc07f)  // lgkmcnt(0), vm/exp free

// fp32 -> bf16 round-to-nearest-even (bit trick; inputs are normal floats)
__device__ __forceinline__ unsigned short f2bf(float f) {
    union { float f; unsigned int u; } v; v.f = f;
    unsigned int u = v.u;
    unsigned int r = u + 0x7FFFu + ((u >> 16) & 1u);
    return (unsigned short)(r >> 16);
}

// async global->LDS, 16B per lane. LDS dest = wave-uniform base + lane*16.
__device__ __forceinline__ void gload16(const void* g, void* l) {
    __builtin_amdgcn_global_load_lds(
        (const __attribute__((address_space(1))) void*)g,
        (__attribute__((address_space(3))) void*)l,
        16, 0, 0);
}

// ---------------------------------------------------------------------------
// Kernel 1a: x fp32 -> bf16 (blocks 0..8191), + mixed bias (blocks 8192..8223)
// ---------------------------------------------------------------------------
__global__ __launch_bounds__(256) void xconv_kernel(
    const float* __restrict__ x, const float* __restrict__ p,
    const float* __restrict__ bias,
    unsigned short* __restrict__ xb, float* __restrict__ mb)
{
    const long gid = (long)blockIdx.x * 256 + threadIdx.x;
    const long NX = (long)BB * SS * DIN / 8;   // 2,097,152 threads, 8 elem each
    if (gid < NX) {
        const float4* xv = (const float4*)x;
        float4 v0 = xv[gid * 2 + 0];
        float4 v1 = xv[gid * 2 + 1];
        uint4 o;
        o.x = (unsigned)f2bf(v0.x) | ((unsigned)f2bf(v0.y) << 16);
        o.y = (unsigned)f2bf(v0.z) | ((unsigned)f2bf(v0.w) << 16);
        o.z = (unsigned)f2bf(v1.x) | ((unsigned)f2bf(v1.y) << 16);
        o.w = (unsigned)f2bf(v1.z) | ((unsigned)f2bf(v1.w) << 16);
        ((uint4*)xb)[gid] = o;
    } else {
        const long t = gid - NX;               // 0..8191: mixed bias
        if (t < (long)BB * DOUT) {
            const int b = (int)(t >> 10), i = (int)(t & 1023);
            float s = 0.f;
            #pragma unroll
            for (int n = 0; n < NEXP; ++n) s += p[b * NEXP + n] * bias[n * DOUT + i];
            mb[t] = s;
        }
    }
}

// ---------------------------------------------------------------------------
// Kernel 1b: mixed_w[b] = sum_n p[b,n] W[n] -> bf16.  262,144 threads,
// each handles 4 consecutive elements for all 8 batches (reads W once).
// ---------------------------------------------------------------------------
__global__ __launch_bounds__(256) void wmix_kernel(
    const float* __restrict__ p, const float* __restrict__ w,
    unsigned short* __restrict__ mw)
{
    __shared__ float sp[BB * NEXP];
    const int tid = threadIdx.x;
    if (tid < BB * NEXP) sp[tid] = p[tid];
    __syncthreads();

    const long t  = (long)blockIdx.x * 256 + tid;   // 0..262143
    const long j4 = t * 4;
    float acc[BB][4];
    #pragma unroll
    for (int b = 0; b < BB; ++b)
        #pragma unroll
        for (int k = 0; k < 4; ++k) acc[b][k] = 0.f;
    #pragma unroll
    for (int n = 0; n < NEXP; ++n) {
        float4 wv = *(const float4*)(w + (long)n * DOUT * DIN + j4);
        #pragma unroll
        for (int b = 0; b < BB; ++b) {
            float pb = sp[b * NEXP + n];
            acc[b][0] += pb * wv.x; acc[b][1] += pb * wv.y;
            acc[b][2] += pb * wv.z; acc[b][3] += pb * wv.w;
        }
    }
    #pragma unroll
    for (int b = 0; b < BB; ++b) {
        uint2 o;
        o.x = (unsigned)f2bf(acc[b][0]) | ((unsigned)f2bf(acc[b][1]) << 16);
        o.y = (unsigned)f2bf(acc[b][2]) | ((unsigned)f2bf(acc[b][3]) << 16);
        *(uint2*)(mw + (long)b * DOUT * DIN + j4) = o;
    }
}

// ---------------------------------------------------------------------------
// Kernel 2: batched GEMM  out[b] = x_bf16[b] (S x K) * mixed_w[b]^T + mixed_b[b]
// RESTRUCTURED K-loop: per-wave PRIVATE staging, NO __syncthreads in the loop.
// Each wave owns a 64x64 A sub-tile + 64x64 B sub-tile (16 KB private LDS),
// stages them itself with global_load_lds, and orders only its own counters:
//   s_waitcnt lgkmcnt(0)  -- my ds_reads of iter i-1 done -> safe to overwrite
//   s_waitcnt vmcnt(0)    -- my DMA done -> safe to ds_read
// Waves never gang-stall on a block-wide barrier drain (the m97 plateau);
// the SIMD can always issue another resident wave's MFMAs during a drain.
// LDS 64 KB/block -> 2 blocks/CU (8 waves/CU).
// Grid = (B, N, M): linear block id % 8 == batch -> per-XCD L2 residency.
// XOR swizzle (col-group ^ row&7) as in R3 -> 0 bank conflicts.
// ---------------------------------------------------------------------------
__global__ __launch_bounds__(256) void gemm_kernel(
    const unsigned short* __restrict__ xb,   // [B][S][DIN] bf16
    const unsigned short* __restrict__ mw,   // [B][DOUT][DIN] bf16
    const float* __restrict__ mb,            // [B][DOUT] fp32
    float* __restrict__ out)                 // [B][S][DOUT] fp32
{
    __shared__ __align__(16) unsigned short sA[4][64 * 64];  // 32 KB (8 KB/wave)
    __shared__ __align__(16) unsigned short sB[4][64 * 64];  // 32 KB

    const int tid  = threadIdx.x;
    const int wave = tid >> 6;
    const int lane = tid & 63;
    const int b    = blockIdx.x;          // batch -> XCD (id % 8 == b)
    const int tileN = blockIdx.y * 128;   // over DOUT
    const int tileM = blockIdx.z * 128;   // over S

    const unsigned short* Ag = xb + (long)b * SS * DIN;
    const unsigned short* Bg = mw + (long)b * DOUT * DIN;

    const int q     = lane >> 4;     // quad 0..3
    const int r16   = lane & 15;
    const int mBase = tileM + 64 * (wave >> 1);   // this wave's absolute M origin
    const int nBase = tileN + 64 * (wave & 1);    // this wave's absolute N origin

    // staging: wave stages its own 64x64 tiles as 8 chunks of 1 KB (8 rows x 64)
    const int sRow   = lane >> 3;                    // 0..7 row within chunk
    const int sColSw = (((lane & 7) ^ sRow) * 8);    // XOR-swizzled source column

    unsigned short* myA = &sA[wave][0];
    unsigned short* myB = &sB[wave][0];

    const int swz = (r16 & 7);   // reader swizzle (row & 7; frag rows = 16i + r16)

    floatx4 acc[4][4];
    #pragma unroll
    for (int mi = 0; mi < 4; ++mi)
        #pragma unroll
        for (int ni = 0; ni < 4; ++ni)
            acc[mi][ni] = (floatx4){0.f, 0.f, 0.f, 0.f};

    for (int k0 = 0; k0 < DIN; k0 += 64) {
        WAIT_LGKM0();   // my ds_reads of the previous iter have completed
        #pragma unroll
        for (int c = 0; c < 8; ++c) {
            const int row = c * 8 + sRow;            // 0..63 local row
            gload16(Ag + (long)(mBase + row) * DIN + k0 + sColSw, myA + c * 512);
            gload16(Bg + (long)(nBase + row) * DIN + k0 + sColSw, myB + c * 512);
        }
        WAIT_VM0();     // my DMA into myA/myB has landed

        #pragma unroll
        for (int kk = 0; kk < 64; kk += 32) {
            const int gA = ((kk >> 3) + q);          // logical 16B group 0..7
            bf16x8 af[4], bfv[4];
            #pragma unroll
            for (int i = 0; i < 4; ++i)
                af[i] = *(const bf16x8*)&myA[(16 * i + r16) * 64 + ((gA ^ swz) * 8)];
            #pragma unroll
            for (int i = 0; i < 4; ++i)
                bfv[i] = *(const bf16x8*)&myB[(16 * i + r16) * 64 + ((gA ^ swz) * 8)];
            #pragma unroll
            for (int mi = 0; mi < 4; ++mi)
                #pragma unroll
                for (int ni = 0; ni < 4; ++ni)
                    acc[mi][ni] = __builtin_amdgcn_mfma_f32_16x16x32_bf16(
                        af[mi], bfv[ni], acc[mi][ni], 0, 0, 0);
        }
    }

    // epilogue: C[m][n] = acc + mixed_b[b][n]
    float bv[4];
    #pragma unroll
    for (int ni = 0; ni < 4; ++ni)
        bv[ni] = mb[b * DOUT + nBase + 16 * ni + r16];

    #pragma unroll
    for (int mi = 0; mi < 4; ++mi) {
        #pragma unroll
        for (int rr = 0; rr < 4; ++rr) {
            const int row = mBase + 16 * mi + q * 4 + rr;
            float* orow = out + (long)b * SS * DOUT + (long)row * DOUT;
            #pragma unroll
            for (int ni = 0; ni < 4; ++ni)
                orow[nBase + 16 * ni + r16] = acc[mi][ni][rr] + bv[ni];
        }
    }
}

extern "C" void kernel_launch(void* const* d_in, const int* in_sizes, int n_in,
                              void* d_out, int out_size, void* d_ws, size_t ws_size,
                              hipStream_t stream) {
    const float* x    = (const float*)d_in[0];   // [8,2048,1024]
    const float* p    = (const float*)d_in[1];   // [8,16]
    const float* w    = (const float*)d_in[2];   // [16,1024,1024]
    const float* bias = (const float*)d_in[3];   // [16,1024]
    float* out = (float*)d_out;                  // [8,2048,1024]

    // workspace layout: x_bf16 (32 MiB) | mixed_w bf16 (16 MiB) | mixed_b fp32 (32 KiB)
    unsigned short* xb = (unsigned short*)d_ws;
    unsigned short* mw = (unsigned short*)((char*)d_ws + (size_t)33554432);
    float*          mb = (float*)((char*)d_ws + (size_t)33554432 + 16777216);

    xconv_kernel<<<dim3(8192 + 32), 256, 0, stream>>>(x, p, bias, xb, mb);
    wmix_kernel<<<dim3(1024), 256, 0, stream>>>(p, w, mw);

    dim3 ggrid(BB, DOUT / 128, SS / 128);        // (8,8,16) = 1024 blocks
    gemm_kernel<<<ggrid, 256, 0, stream>>>(xb, mw, mb, out);
}

// Round 5
// 212.165 us; speedup vs baseline: 1.0337x; 1.0337x over previous
//
#include <hip/hip_runtime.h>
#include <hip/hip_bf16.h>
#include <stdint.h>

// Problem constants
#define BB 8
#define SS 2048
#define NEXP 16
#define DIN 1024
#define DOUT 1024

typedef short bf16x8 __attribute__((ext_vector_type(8)));
typedef float floatx4 __attribute__((ext_vector_type(4)));

// fp32 -> bf16 round-to-nearest-even (bit trick; inputs are normal floats)
__device__ __forceinline__ unsigned short f2bf(float f) {
    union { float f; unsigned int u; } v; v.f = f;
    unsigned int u = v.u;
    unsigned int r = u + 0x7FFFu + ((u >> 16) & 1u);
    return (unsigned short)(r >> 16);
}

// async global->LDS, 16B per lane. LDS dest = wave-uniform base + lane*16.
__device__ __forceinline__ void gload16(const void* g, void* l) {
    __builtin_amdgcn_global_load_lds(
        (const __attribute__((address_space(1))) void*)g,
        (__attribute__((address_space(3))) void*)l,
        16, 0, 0);
}

// ---------------------------------------------------------------------------
// Kernel 1 (fused prep, one dispatch so the three jobs overlap on the machine):
//  blocks [0, 8192):    x fp32 -> bf16  (2,097,152 threads x 8 elem)
//  blocks [8192, 9216): mixed_w[b] = sum_n p[b,n] W[n] -> bf16 (262,144 thr x 4 elem x 8 b)
//  blocks [9216, 9248): mixed_b (8,192 threads)
// ---------------------------------------------------------------------------
__global__ __launch_bounds__(256) void prep_kernel(
    const float* __restrict__ x, const float* __restrict__ p,
    const float* __restrict__ w, const float* __restrict__ bias,
    unsigned short* __restrict__ xb, unsigned short* __restrict__ mw,
    float* __restrict__ mb)
{
    const int tid = threadIdx.x;
    const int blk = blockIdx.x;

    if (blk < 8192) {                       // ---- x convert ----
        const long gid = (long)blk * 256 + tid;
        const float4* xv = (const float4*)x;
        float4 v0 = xv[gid * 2 + 0];
        float4 v1 = xv[gid * 2 + 1];
        uint4 o;
        o.x = (unsigned)f2bf(v0.x) | ((unsigned)f2bf(v0.y) << 16);
        o.y = (unsigned)f2bf(v0.z) | ((unsigned)f2bf(v0.w) << 16);
        o.z = (unsigned)f2bf(v1.x) | ((unsigned)f2bf(v1.y) << 16);
        o.w = (unsigned)f2bf(v1.z) | ((unsigned)f2bf(v1.w) << 16);
        ((uint4*)xb)[gid] = o;
    } else if (blk < 9216) {                // ---- weight mix ----
        __shared__ float sp[BB * NEXP];
        if (tid < BB * NEXP) sp[tid] = p[tid];
        __syncthreads();
        const long t  = (long)(blk - 8192) * 256 + tid;   // 0..262143
        const long j4 = t * 4;
        float acc[BB][4];
        #pragma unroll
        for (int b = 0; b < BB; ++b)
            #pragma unroll
            for (int k = 0; k < 4; ++k) acc[b][k] = 0.f;
        #pragma unroll
        for (int n = 0; n < NEXP; ++n) {
            float4 wv = *(const float4*)(w + (long)n * DOUT * DIN + j4);
            #pragma unroll
            for (int b = 0; b < BB; ++b) {
                float pb = sp[b * NEXP + n];
                acc[b][0] += pb * wv.x; acc[b][1] += pb * wv.y;
                acc[b][2] += pb * wv.z; acc[b][3] += pb * wv.w;
            }
        }
        #pragma unroll
        for (int b = 0; b < BB; ++b) {
            uint2 o;
            o.x = (unsigned)f2bf(acc[b][0]) | ((unsigned)f2bf(acc[b][1]) << 16);
            o.y = (unsigned)f2bf(acc[b][2]) | ((unsigned)f2bf(acc[b][3]) << 16);
            *(uint2*)(mw + (long)b * DOUT * DIN + j4) = o;
        }
    } else {                                // ---- bias mix ----
        const long t = (long)(blk - 9216) * 256 + tid;    // 0..8191
        const int b = (int)(t >> 10), i = (int)(t & 1023);
        float s = 0.f;
        #pragma unroll
        for (int n = 0; n < NEXP; ++n) s += p[b * NEXP + n] * bias[n * DOUT + i];
        mb[t] = s;
    }
}

// ---------------------------------------------------------------------------
// Kernel 2: batched GEMM  out[b] = x_bf16[b] (S x K) * mixed_w[b]^T + mixed_b[b]
// R3 structure (block-shared staging, 2 barriers/iter) + FULLY UNROLLED K-loop:
//  - 8 global source base pointers hoisted; per-iter offset 128*t bytes folds
//    into the 13-bit immediate of global_load_lds (max 1920 <= 4095).
//  - all LDS read addresses loop-invariant -> hoisted to VGPRs by LICM.
//  => per-iteration VALU ~ 0 (R3 showed VALUBusy 33% > MfmaUtil 26%: address
//     recomputation was co-limiting with MFMA).
// Grid = (B, N, M): linear block id % 8 == batch -> per-XCD L2 residency
// (R2: FETCH 139->33 MB). XOR swizzle (group ^ row&7) -> 0 bank conflicts (R3).
// LDS 32 KB -> grid-limited 4 blocks/CU (16 waves).
// ---------------------------------------------------------------------------
__global__ __launch_bounds__(256) void gemm_kernel(
    const unsigned short* __restrict__ xb,   // [B][S][DIN] bf16
    const unsigned short* __restrict__ mw,   // [B][DOUT][DIN] bf16
    const float* __restrict__ mb,            // [B][DOUT] fp32
    float* __restrict__ out)                 // [B][S][DOUT] fp32
{
    __shared__ __align__(16) unsigned short sA[128 * 64];  // 16 KB
    __shared__ __align__(16) unsigned short sB[128 * 64];  // 16 KB

    const int tid  = threadIdx.x;
    const int wave = tid >> 6;
    const int lane = tid & 63;
    const int b    = blockIdx.x;          // batch -> XCD (id % 8 == b)
    const int tileN = blockIdx.y * 128;   // over DOUT
    const int tileM = blockIdx.z * 128;   // over S

    const unsigned short* Ag = xb + (long)b * SS * DIN;
    const unsigned short* Bg = mw + (long)b * DOUT * DIN;

    const int q     = lane >> 4;     // quad 0..3
    const int r16   = lane & 15;
    const int mBase = 64 * (wave >> 1);
    const int nBase = 64 * (wave & 1);

    // staging: each wave owns 4 chunks of 1KB (8 rows x 64 bf16) for A and B
    const int sRow   = lane >> 3;                    // 0..7 row within chunk
    const int sColSw = (((lane & 7) ^ sRow) * 8);    // XOR-swizzled source column

    // hoisted global source bases + LDS destinations (loop-invariant)
    const unsigned short* aSrc[4]; const unsigned short* bSrc[4];
    unsigned short* aDst[4]; unsigned short* bDst[4];
    #pragma unroll
    for (int c = 0; c < 4; ++c) {
        const int chunk = wave * 4 + c;              // 0..15
        const int row   = chunk * 8 + sRow;          // 0..127
        aSrc[c] = Ag + (long)(tileM + row) * DIN + sColSw;
        bSrc[c] = Bg + (long)(tileN + row) * DIN + sColSw;
        aDst[c] = &sA[chunk * 512];
        bDst[c] = &sB[chunk * 512];
    }

    // reader: XOR-swizzled 16B-group offsets for the two kk halves (invariant)
    const int swz  = r16 & 7;
    const int colK0 = ((q)     ^ swz) * 8;           // kk = 0..31  (group q)
    const int colK1 = ((q + 4) ^ swz) * 8;           // kk = 32..63 (group q+4)

    floatx4 acc[4][4];
    #pragma unroll
    for (int mi = 0; mi < 4; ++mi)
        #pragma unroll
        for (int ni = 0; ni < 4; ++ni)
            acc[mi][ni] = (floatx4){0.f, 0.f, 0.f, 0.f};

    #pragma unroll
    for (int t = 0; t < 16; ++t) {                   // k0 = 64*t, fully unrolled
        __syncthreads();   // previous tile's compute done before overwrite
        #pragma unroll
        for (int c = 0; c < 4; ++c) {
            gload16(aSrc[c] + 64 * t, aDst[c]);      // +128*t bytes -> imm offset
            gload16(bSrc[c] + 64 * t, bDst[c]);
        }
        __syncthreads();   // loads visible

        #pragma unroll
        for (int kh = 0; kh < 2; ++kh) {
            const int col = kh ? colK1 : colK0;
            bf16x8 af[4], bfv[4];
            #pragma unroll
            for (int i = 0; i < 4; ++i)
                af[i] = *(const bf16x8*)&sA[(mBase + 16 * i + r16) * 64 + col];
            #pragma unroll
            for (int i = 0; i < 4; ++i)
                bfv[i] = *(const bf16x8*)&sB[(nBase + 16 * i + r16) * 64 + col];
            #pragma unroll
            for (int mi = 0; mi < 4; ++mi)
                #pragma unroll
                for (int ni = 0; ni < 4; ++ni)
                    acc[mi][ni] = __builtin_amdgcn_mfma_f32_16x16x32_bf16(
                        af[mi], bfv[ni], acc[mi][ni], 0, 0, 0);
        }
    }

    // epilogue: C[m][n] = acc + mixed_b[b][n]
    float bv[4];
    #pragma unroll
    for (int ni = 0; ni < 4; ++ni)
        bv[ni] = mb[b * DOUT + tileN + nBase + 16 * ni + r16];

    #pragma unroll
    for (int mi = 0; mi < 4; ++mi) {
        #pragma unroll
        for (int rr = 0; rr < 4; ++rr) {
            const int row = tileM + mBase + 16 * mi + q * 4 + rr;
            float* orow = out + (long)b * SS * DOUT + (long)row * DOUT;
            #pragma unroll
            for (int ni = 0; ni < 4; ++ni)
                orow[tileN + nBase + 16 * ni + r16] = acc[mi][ni][rr] + bv[ni];
        }
    }
}

extern "C" void kernel_launch(void* const* d_in, const int* in_sizes, int n_in,
                              void* d_out, int out_size, void* d_ws, size_t ws_size,
                              hipStream_t stream) {
    const float* x    = (const float*)d_in[0];   // [8,2048,1024]
    const float* p    = (const float*)d_in[1];   // [8,16]
    const float* w    = (const float*)d_in[2];   // [16,1024,1024]
    const float* bias = (const float*)d_in[3];   // [16,1024]
    float* out = (float*)d_out;                  // [8,2048,1024]

    // workspace layout: x_bf16 (32 MiB) | mixed_w bf16 (16 MiB) | mixed_b fp32 (32 KiB)
    unsigned short* xb = (unsigned short*)d_ws;
    unsigned short* mw = (unsigned short*)((char*)d_ws + (size_t)33554432);
    float*          mb = (float*)((char*)d_ws + (size_t)33554432 + 16777216);

    prep_kernel<<<dim3(9248), 256, 0, stream>>>(x, p, w, bias, xb, mw, mb);

    dim3 ggrid(BB, DOUT / 128, SS / 128);        // (8,8,16) = 1024 blocks
    gemm_kernel<<<ggrid, 256, 0, stream>>>(xb, mw, mb, out);
}